// Round 8
// baseline (157.298 us; speedup 1.0000x reference)
//
#include <hip/hip_runtime.h>
#include <hip/hip_bf16.h>
#include <stdint.h>

// B=32768 queries, M=4096 memory rows, D=128.
//   logits = Q @ M^T ; attn = softmax(logits) ; out = attn @ M
// Flash-style fused kernel. bf16x3-split MFMA QK^T (near-fp32), bf16 PV.
// v8: occupancy push. Diagnosis: at 2 blocks/CU the per-wave serial tails
// (LDS queue -> 24-dep QK chain -> softmax) leave the round ~58% idle.
// Changes: (1) single-chain QK (one accumulator: AGPR 96->80) and
// __launch_bounds__(256,3) -> 168-reg cap, ~160 live; (2) 3-way M-split,
// 768 blocks = exactly 3 blocks/CU (12 waves/CU), zero scheduling tail;
// LDS 3x48KB = 144 <= 160KB; (3) part-0 partials written into d_out so
// ws stays ~36MB; 3-way merge kernel; (4) T5 setprio around MFMA bursts.

typedef float   f32x16 __attribute__((ext_vector_type(16)));
typedef short   bf16x8 __attribute__((ext_vector_type(8)));
typedef uint32_t u32;

#define AS1 __attribute__((address_space(1)))
#define AS3 __attribute__((address_space(3)))

#define D_DIM 128
#define B_ROWS 32768
#define TILE_HW 12288     // halfwords per 32-row tile: [khi 4096|klo 4096|v 4096]

#if __has_builtin(__builtin_amdgcn_exp2f)
#define EXP2F(x) __builtin_amdgcn_exp2f(x)
#else
#define EXP2F(x) exp2f(x)
#endif

__device__ __forceinline__ uint16_t f32_to_bf16_rne(float x) {
    u32 u = __float_as_uint(x);
    u32 r = u + 0x7fffu + ((u >> 16) & 1u);
    return (uint16_t)(r >> 16);
}
__device__ __forceinline__ float bf16_to_f32(uint16_t h) {
    return __uint_as_float(((u32)h) << 16);
}

// ---------------------------------------------------------------------------
// Prep: memory -> interleaved fragment-linear bf16 tiles in d_ws.
// Per tile mt (24576 B): [0,8K) khi frags, [8K,16K) klo frags, [16K,24K) v frags.
// ---------------------------------------------------------------------------
__global__ void prep_frags(const float* __restrict__ mem,
                           uint16_t* __restrict__ kv) {
    int t = blockIdx.x * blockDim.x + threadIdx.x;  // 0..65535
    int lane = t & 63;
    int fi = t >> 6;                                // 0..1023
    int f8 = fi & 7, mt = fi >> 3;
    size_t base = (size_t)mt * TILE_HW;
    {   // K fragment (hi/lo split)
        int m  = mt * 32 + (lane & 31);
        int d0 = f8 * 16 + (lane >> 5) * 8;
        const float* src = mem + (size_t)m * D_DIM + d0;
        #pragma unroll
        for (int e = 0; e < 8; ++e) {
            float x = src[e];
            uint16_t hb = f32_to_bf16_rne(x);
            kv[base + f8 * 512 + lane * 8 + e] = hb;
            kv[base + 4096 + f8 * 512 + lane * 8 + e] =
                f32_to_bf16_rne(x - bf16_to_f32(hb));
        }
    }
    {   // V^T fragment (plain bf16)
        int dt = fi & 3, ks = (fi >> 2) & 1;
        int d  = dt * 32 + (lane & 31);
        int m0 = mt * 32 + ks * 16 + (lane >> 5) * 8;
        #pragma unroll
        for (int e = 0; e < 8; ++e)
            kv[base + 8192 + f8 * 512 + lane * 8 + e] =
                f32_to_bf16_rne(mem[(size_t)(m0 + e) * D_DIM + d]);
    }
}

// ---------------------------------------------------------------------------
// Main kernel: 768 blocks x 256 threads (4 waves). Block bx: q-chunk bx/3,
// memory part bx%3 (tiles 43/43/42). LDS double-buffered 24KB tiles (48 KB).
// ---------------------------------------------------------------------------

#define STAGE(t_, wb_) do {                                                   \
    const char* g_ = (const char*)(kv + (size_t)(tilebase + (t_)) * TILE_HW); \
    char* l_ = (char*)&sbuf[wb_][0];                                          \
    _Pragma("unroll")                                                         \
    for (int j_ = 0; j_ < 6; ++j_) {                                          \
        int ch_ = wave * 6 + j_;                                              \
        __builtin_amdgcn_global_load_lds(                                     \
            (const AS1 char*)(g_ + ch_ * 1024 + lane * 16),                   \
            (AS3 char*)(l_ + ch_ * 1024), 16, 0, 0);                          \
    }                                                                         \
} while (0)

#define MFMA_BF16(a_, b_, c_) __builtin_amdgcn_mfma_f32_32x32x16_bf16(a_, b_, c_, 0, 0, 0)

#define PSTORE_TILE(Ot_, t_) do {                                             \
    _Pragma("unroll")                                                         \
    for (int g_ = 0; g_ < 4; ++g_) {                                          \
        float4 v_ = { Ot_[4*g_+0], Ot_[4*g_+1], Ot_[4*g_+2], Ot_[4*g_+3] };   \
        int d_ = (t_) * 32 + 8 * g_ + 4 * hi32;                               \
        *(float4*)(prow + d_) = v_;                                           \
    }                                                                         \
} while (0)

__global__ __launch_bounds__(256, 3)
void attn_main(const float* __restrict__ qin,
               const uint16_t* __restrict__ kv,
               float* __restrict__ out0,      // part-0 partial O (= d_out)
               float* __restrict__ pout12,    // [2][B_ROWS][128] parts 1,2
               float2* __restrict__ pml) {    // [3][B_ROWS] (m, l)
    __shared__ uint16_t sbuf[2][TILE_HW];   // 2 x 24 KB = 48 KB

    const int lane = threadIdx.x & 63;
    const int wave = threadIdx.x >> 6;
    const int bx   = blockIdx.x;
    const int part = bx % 3;
    const int tilebase = (part == 0) ? 0 : (part == 1 ? 43 : 86);
    const int ntiles   = (part == 2) ? 42 : 43;
    const int q0   = (bx / 3) * 128 + wave * 32;
    const int qrow = q0 + (lane & 31);
    const int hi32 = lane >> 5;

    // Q prep: scale by log2(e), split into bf16 hi/lo (B-frag of Sᵀ MFMA).
    bf16x8 qhi[8], qlo[8];
    {
        const float LOG2E = 1.44269504088896340736f;
        #pragma unroll
        for (int kk = 0; kk < 8; ++kk) {
            const float* src = qin + (size_t)qrow * D_DIM + kk * 16 + hi32 * 8;
            float4 a = *(const float4*)(src);
            float4 b = *(const float4*)(src + 4);
            float xs[8] = {a.x, a.y, a.z, a.w, b.x, b.y, b.z, b.w};
            #pragma unroll
            for (int e = 0; e < 8; ++e) {
                float x = xs[e] * LOG2E;
                uint16_t hb = f32_to_bf16_rne(x);
                qhi[kk][e] = (short)hb;
                qlo[kk][e] = (short)f32_to_bf16_rne(x - bf16_to_f32(hb));
            }
        }
    }

    f32x16 O0, O1, O2, O3;
    #pragma unroll
    for (int i = 0; i < 16; ++i) { O0[i]=0.f; O1[i]=0.f; O2[i]=0.f; O3[i]=0.f; }
    float m_run = -1e30f, l_run = 0.f;

    STAGE(0, 0);
    __syncthreads();

    #pragma unroll 1
    for (int t = 0; t < ntiles; ++t) {
        const int rb = t & 1;
        if (t + 1 < ntiles) STAGE(t + 1, rb ^ 1);
        const uint16_t* bp = &sbuf[rb][0] + lane * 8;

        // ---- QK^T: bf16x3 split, single accumulator chain (reg diet) ----
        f32x16 s;
        #pragma unroll
        for (int i = 0; i < 16; ++i) s[i] = 0.f;
        __builtin_amdgcn_s_setprio(1);
        #pragma unroll
        for (int kk = 0; kk < 8; ++kk) {
            bf16x8 kh = *(const bf16x8*)(bp + kk * 512);
            bf16x8 kl = *(const bf16x8*)(bp + 4096 + kk * 512);
            s = MFMA_BF16(kh, qhi[kk], s);
            s = MFMA_BF16(kh, qlo[kk], s);
            s = MFMA_BF16(kl, qhi[kk], s);
        }
        __builtin_amdgcn_s_setprio(0);

        // ---- online softmax (q = lane&31; pair lane lane^32 has other 16 m) ----
        {
            float a0=fmaxf(s[0],s[1]),  a1=fmaxf(s[2],s[3]);
            float a2=fmaxf(s[4],s[5]),  a3=fmaxf(s[6],s[7]);
            float a4=fmaxf(s[8],s[9]),  a5=fmaxf(s[10],s[11]);
            float a6=fmaxf(s[12],s[13]),a7=fmaxf(s[14],s[15]);
            float tmax = fmaxf(fmaxf(fmaxf(a0,a1),fmaxf(a2,a3)),
                               fmaxf(fmaxf(a4,a5),fmaxf(a6,a7)));
            tmax = fmaxf(tmax, __shfl_xor(tmax, 32));
            if (__any(tmax > m_run + 8.0f)) {     // defer-max (T13)
                float mn = fmaxf(m_run, tmax);
                float fr = EXP2F(m_run - mn);
                m_run = mn; l_run *= fr;
                #pragma unroll
                for (int r = 0; r < 16; ++r) {
                    O0[r] *= fr; O1[r] *= fr; O2[r] *= fr; O3[r] *= fr;
                }
            }
        }
        #pragma unroll
        for (int r = 0; r < 16; ++r) s[r] = EXP2F(s[r] - m_run);
        {
            float q0s=s[0]+s[1],  q1s=s[2]+s[3],  q2s=s[4]+s[5],  q3s=s[6]+s[7];
            float q4s=s[8]+s[9],  q5s=s[10]+s[11],q6s=s[12]+s[13],q7s=s[14]+s[15];
            l_run += ((q0s+q1s)+(q2s+q3s)) + ((q4s+q5s)+(q6s+q7s));
        }

        // ---- P(f32) -> bf16 B-frags via cvt_pk + permlane32_swap (T12) ----
        u32 c_[8];
        #pragma unroll
        for (int j = 0; j < 8; ++j)
            asm("v_cvt_pk_bf16_f32 %0, %1, %2"
                : "=v"(c_[j]) : "v"(s[2*j]), "v"(s[2*j+1]));
        asm("v_permlane32_swap_b32 %0, %1" : "+v"(c_[0]), "+v"(c_[2]));
        asm("v_permlane32_swap_b32 %0, %1" : "+v"(c_[1]), "+v"(c_[3]));
        asm("v_permlane32_swap_b32 %0, %1" : "+v"(c_[4]), "+v"(c_[6]));
        asm("v_permlane32_swap_b32 %0, %1" : "+v"(c_[5]), "+v"(c_[7]));
        bf16x8 pf0, pf1;
        { u32 w[4] = {c_[0], c_[1], c_[2], c_[3]}; __builtin_memcpy(&pf0, w, 16); }
        { u32 w[4] = {c_[4], c_[5], c_[6], c_[7]}; __builtin_memcpy(&pf1, w, 16); }

        // ---- PV: Oᵀ[d][q] += Vᵀ·Pᵀ, V fragments streamed from LDS ----
        __builtin_amdgcn_s_setprio(1);
        {
            bf16x8 vf;
            vf = *(const bf16x8*)(bp + 8192 + 0*512); O0 = MFMA_BF16(vf, pf0, O0);
            vf = *(const bf16x8*)(bp + 8192 + 1*512); O1 = MFMA_BF16(vf, pf0, O1);
            vf = *(const bf16x8*)(bp + 8192 + 2*512); O2 = MFMA_BF16(vf, pf0, O2);
            vf = *(const bf16x8*)(bp + 8192 + 3*512); O3 = MFMA_BF16(vf, pf0, O3);
            vf = *(const bf16x8*)(bp + 8192 + 4*512); O0 = MFMA_BF16(vf, pf1, O0);
            vf = *(const bf16x8*)(bp + 8192 + 5*512); O1 = MFMA_BF16(vf, pf1, O1);
            vf = *(const bf16x8*)(bp + 8192 + 6*512); O2 = MFMA_BF16(vf, pf1, O2);
            vf = *(const bf16x8*)(bp + 8192 + 7*512); O3 = MFMA_BF16(vf, pf1, O3);
        }
        __builtin_amdgcn_s_setprio(0);
        __syncthreads();
    }

    // ---- partial store (un-normalized O, plus m,l) ----
    l_run += __shfl_xor(l_run, 32);     // pair-lane partial sums
    float* prow = (part == 0 ? out0
                             : pout12 + (size_t)(part - 1) * B_ROWS * D_DIM)
                  + (size_t)qrow * D_DIM;
    PSTORE_TILE(O0, 0); PSTORE_TILE(O1, 1);
    PSTORE_TILE(O2, 2); PSTORE_TILE(O3, 3);
    if (lane < 32) {
        pml[(size_t)part * B_ROWS + qrow] = make_float2(m_run, l_run);
    }
}

// ---------------------------------------------------------------------------
// Merge: out = sum_p(P_p * w_p) / sum_p(l_p * w_p), w_p = exp2(m_p - max).
// P_0 lives in d_out (in-place: each thread reads its float4, then writes).
// ---------------------------------------------------------------------------
__global__ __launch_bounds__(256)
void merge_parts(const float* __restrict__ pout12,
                 const float2* __restrict__ pml,
                 float* __restrict__ out) {
    int idx  = blockIdx.x * 256 + threadIdx.x;   // 0 .. 2^20-1
    int row  = idx >> 5;
    int c4   = idx & 31;
    float2 a = pml[row];
    float2 b = pml[B_ROWS + row];
    float2 c = pml[2 * B_ROWS + row];
    float mn = fmaxf(fmaxf(a.x, b.x), c.x);
    float wa = EXP2F(a.x - mn);
    float wb = EXP2F(b.x - mn);
    float wc = EXP2F(c.x - mn);
    float rinv = 1.0f / (a.y * wa + b.y * wb + c.y * wc);
    float4* O  = (float4*)(out + (size_t)row * D_DIM) + c4;
    const float4* P1 = (const float4*)(pout12 + (size_t)row * D_DIM) + c4;
    const float4* P2 = (const float4*)(pout12 + ((size_t)B_ROWS + row) * D_DIM) + c4;
    float4 p0 = *O, p1 = *P1, p2 = *P2;
    float4 v;
    v.x = (p0.x * wa + p1.x * wb + p2.x * wc) * rinv;
    v.y = (p0.y * wa + p1.y * wb + p2.y * wc) * rinv;
    v.z = (p0.z * wa + p1.z * wb + p2.z * wc) * rinv;
    v.w = (p0.w * wa + p1.w * wb + p2.w * wc) * rinv;
    *O = v;
}

extern "C" void kernel_launch(void* const* d_in, const int* in_sizes, int n_in,
                              void* d_out, int out_size, void* d_ws, size_t ws_size,
                              hipStream_t stream) {
    const float* local_stats = (const float*)d_in[0];   // [32768,128] f32
    const float* memory      = (const float*)d_in[1];   // [4096,128]  f32
    float* out = (float*)d_out;                         // [32768,128] f32

    // ws layout: kv frags 3MB | parts 1,2 partial O 32MB | pml 0.75MB
    uint16_t* kv    = (uint16_t*)d_ws;
    float*   pout12 = (float*)((char*)d_ws + 3 * 1024 * 1024);
    float2*  pml    = (float2*)((char*)pout12 + (size_t)2 * B_ROWS * D_DIM * 4);

    prep_frags<<<256, 256, 0, stream>>>(memory, kv);
    attn_main<<<768, 256, 0, stream>>>(local_stats, kv, out, pout12, pml);
    merge_parts<<<4096, 256, 0, stream>>>(pout12, pml, out);
}

// Round 9
// 155.748 us; speedup vs baseline: 1.0100x; 1.0100x over previous
//
#include <hip/hip_runtime.h>
#include <hip/hip_bf16.h>
#include <stdint.h>

// B=32768 queries, M=4096 memory rows, D=128.
//   logits = Q @ M^T ; attn = softmax(logits) ; out = attn @ M
// Flash-style fused kernel. bf16x3-split MFMA QK^T (near-fp32), bf16 PV.
// v9: batched LDS reads (T16 cluster style). v8 post-mortem: at 3 blocks/CU
// the 168-reg cap left no room to batch ds_reads -> each kk exposed ~120cyc
// LDS latency; extra TLP bought nothing. Now: 2 blocks/CU (cap 256), all 16
// K-fragment reads issued as one batch into regs (one lgkmcnt drain), then a
// clean 24-MFMA 2-chain burst; V batched before the 8 PV MFMAs (overlays the
// dead K batch regs). M-split 2, 512 blocks = exactly 2/CU. ~246 regs peak.

typedef float   f32x16 __attribute__((ext_vector_type(16)));
typedef short   bf16x8 __attribute__((ext_vector_type(8)));
typedef uint32_t u32;

#define AS1 __attribute__((address_space(1)))
#define AS3 __attribute__((address_space(3)))

#define D_DIM 128
#define B_ROWS 32768
#define TILE_HW 12288     // halfwords per 32-row tile: [khi 4096|klo 4096|v 4096]
#define HALF_TILES 64     // tiles per block

#if __has_builtin(__builtin_amdgcn_exp2f)
#define EXP2F(x) __builtin_amdgcn_exp2f(x)
#else
#define EXP2F(x) exp2f(x)
#endif

__device__ __forceinline__ uint16_t f32_to_bf16_rne(float x) {
    u32 u = __float_as_uint(x);
    u32 r = u + 0x7fffu + ((u >> 16) & 1u);
    return (uint16_t)(r >> 16);
}
__device__ __forceinline__ float bf16_to_f32(uint16_t h) {
    return __uint_as_float(((u32)h) << 16);
}

// ---------------------------------------------------------------------------
// Prep: memory -> interleaved fragment-linear bf16 tiles in d_ws.
// Per tile mt (24576 B): [0,8K) khi frags, [8K,16K) klo frags, [16K,24K) v frags.
// ---------------------------------------------------------------------------
__global__ void prep_frags(const float* __restrict__ mem,
                           uint16_t* __restrict__ kv) {
    int t = blockIdx.x * blockDim.x + threadIdx.x;  // 0..65535
    int lane = t & 63;
    int fi = t >> 6;                                // 0..1023
    int f8 = fi & 7, mt = fi >> 3;
    size_t base = (size_t)mt * TILE_HW;
    {   // K fragment (hi/lo split)
        int m  = mt * 32 + (lane & 31);
        int d0 = f8 * 16 + (lane >> 5) * 8;
        const float* src = mem + (size_t)m * D_DIM + d0;
        #pragma unroll
        for (int e = 0; e < 8; ++e) {
            float x = src[e];
            uint16_t hb = f32_to_bf16_rne(x);
            kv[base + f8 * 512 + lane * 8 + e] = hb;
            kv[base + 4096 + f8 * 512 + lane * 8 + e] =
                f32_to_bf16_rne(x - bf16_to_f32(hb));
        }
    }
    {   // V^T fragment (plain bf16)
        int dt = fi & 3, ks = (fi >> 2) & 1;
        int d  = dt * 32 + (lane & 31);
        int m0 = mt * 32 + ks * 16 + (lane >> 5) * 8;
        #pragma unroll
        for (int e = 0; e < 8; ++e)
            kv[base + 8192 + f8 * 512 + lane * 8 + e] =
                f32_to_bf16_rne(mem[(size_t)(m0 + e) * D_DIM + d]);
    }
}

// ---------------------------------------------------------------------------
// Main kernel: 512 blocks x 256 threads (4 waves). Block bx: q-chunk bx>>1,
// memory half bx&1 (64 tiles). LDS double-buffered 24KB tiles (48 KB).
// ---------------------------------------------------------------------------

#define STAGE(t_, wb_) do {                                                   \
    const char* g_ = (const char*)(kv + (size_t)(tilebase + (t_)) * TILE_HW); \
    char* l_ = (char*)&sbuf[wb_][0];                                          \
    _Pragma("unroll")                                                         \
    for (int j_ = 0; j_ < 6; ++j_) {                                          \
        int ch_ = wave * 6 + j_;                                              \
        __builtin_amdgcn_global_load_lds(                                     \
            (const AS1 char*)(g_ + ch_ * 1024 + lane * 16),                   \
            (AS3 char*)(l_ + ch_ * 1024), 16, 0, 0);                          \
    }                                                                         \
} while (0)

#define MFMA_BF16(a_, b_, c_) __builtin_amdgcn_mfma_f32_32x32x16_bf16(a_, b_, c_, 0, 0, 0)

#define PSTORE_TILE(Ot_, t_) do {                                             \
    _Pragma("unroll")                                                         \
    for (int g_ = 0; g_ < 4; ++g_) {                                          \
        float4 v_ = { Ot_[4*g_+0], Ot_[4*g_+1], Ot_[4*g_+2], Ot_[4*g_+3] };   \
        int d_ = (t_) * 32 + 8 * g_ + 4 * hi32;                               \
        *(float4*)(prow + d_) = v_;                                           \
    }                                                                         \
} while (0)

__global__ __launch_bounds__(256, 2)
void attn_main(const float* __restrict__ qin,
               const uint16_t* __restrict__ kv,
               float* __restrict__ out0,      // part-0 partial O (= d_out)
               float* __restrict__ pout1,     // [B_ROWS][128] part-1 partial
               float2* __restrict__ pml) {    // [2][B_ROWS] (m, l)
    __shared__ uint16_t sbuf[2][TILE_HW];   // 2 x 24 KB = 48 KB

    const int lane = threadIdx.x & 63;
    const int wave = threadIdx.x >> 6;
    const int half = blockIdx.x & 1;
    const int tilebase = half * HALF_TILES;
    const int q0   = (blockIdx.x >> 1) * 128 + wave * 32;
    const int qrow = q0 + (lane & 31);
    const int hi32 = lane >> 5;

    // Q prep: scale by log2(e), split into bf16 hi/lo (B-frag of Sᵀ MFMA).
    bf16x8 qhi[8], qlo[8];
    {
        const float LOG2E = 1.44269504088896340736f;
        #pragma unroll
        for (int kk = 0; kk < 8; ++kk) {
            const float* src = qin + (size_t)qrow * D_DIM + kk * 16 + hi32 * 8;
            float4 a = *(const float4*)(src);
            float4 b = *(const float4*)(src + 4);
            float xs[8] = {a.x, a.y, a.z, a.w, b.x, b.y, b.z, b.w};
            #pragma unroll
            for (int e = 0; e < 8; ++e) {
                float x = xs[e] * LOG2E;
                uint16_t hb = f32_to_bf16_rne(x);
                qhi[kk][e] = (short)hb;
                qlo[kk][e] = (short)f32_to_bf16_rne(x - bf16_to_f32(hb));
            }
        }
    }

    f32x16 O0, O1, O2, O3;
    #pragma unroll
    for (int i = 0; i < 16; ++i) { O0[i]=0.f; O1[i]=0.f; O2[i]=0.f; O3[i]=0.f; }
    float m_run = -1e30f, l_run = 0.f;

    STAGE(0, 0);
    __syncthreads();

    #pragma unroll 1
    for (int t = 0; t < HALF_TILES; ++t) {
        const int rb = t & 1;
        if (t + 1 < HALF_TILES) STAGE(t + 1, rb ^ 1);
        const uint16_t* bp = &sbuf[rb][0] + lane * 8;

        // ---- batch: all 16 K-fragment reads issued back-to-back ----
        bf16x8 kh[8], kl[8];
        #pragma unroll
        for (int kk = 0; kk < 8; ++kk) {
            kh[kk] = *(const bf16x8*)(bp + kk * 512);
            kl[kk] = *(const bf16x8*)(bp + 4096 + kk * 512);
        }

        // ---- QK^T: bf16x3 split, 2-chain burst, all operands in regs ----
        f32x16 sh, sl;
        #pragma unroll
        for (int i = 0; i < 16; ++i) { sh[i] = 0.f; sl[i] = 0.f; }
        __builtin_amdgcn_s_setprio(1);
        #pragma unroll
        for (int kk = 0; kk < 8; ++kk) {
            sh = MFMA_BF16(kh[kk], qhi[kk], sh);
            sl = MFMA_BF16(kh[kk], qlo[kk], sl);
            sl = MFMA_BF16(kl[kk], qhi[kk], sl);
        }
        __builtin_amdgcn_s_setprio(0);
        f32x16 s = sh + sl;   // Sᵀ[m][q], log2-domain logits

        // ---- online softmax (q = lane&31; pair lane lane^32 has other 16 m) ----
        {
            float a0=fmaxf(s[0],s[1]),  a1=fmaxf(s[2],s[3]);
            float a2=fmaxf(s[4],s[5]),  a3=fmaxf(s[6],s[7]);
            float a4=fmaxf(s[8],s[9]),  a5=fmaxf(s[10],s[11]);
            float a6=fmaxf(s[12],s[13]),a7=fmaxf(s[14],s[15]);
            float tmax = fmaxf(fmaxf(fmaxf(a0,a1),fmaxf(a2,a3)),
                               fmaxf(fmaxf(a4,a5),fmaxf(a6,a7)));
            tmax = fmaxf(tmax, __shfl_xor(tmax, 32));
            if (__any(tmax > m_run + 8.0f)) {     // defer-max (T13)
                float mn = fmaxf(m_run, tmax);
                float fr = EXP2F(m_run - mn);
                m_run = mn; l_run *= fr;
                #pragma unroll
                for (int r = 0; r < 16; ++r) {
                    O0[r] *= fr; O1[r] *= fr; O2[r] *= fr; O3[r] *= fr;
                }
            }
        }
        #pragma unroll
        for (int r = 0; r < 16; ++r) s[r] = EXP2F(s[r] - m_run);
        {
            float q0s=s[0]+s[1],  q1s=s[2]+s[3],  q2s=s[4]+s[5],  q3s=s[6]+s[7];
            float q4s=s[8]+s[9],  q5s=s[10]+s[11],q6s=s[12]+s[13],q7s=s[14]+s[15];
            l_run += ((q0s+q1s)+(q2s+q3s)) + ((q4s+q5s)+(q6s+q7s));
        }

        // ---- P(f32) -> bf16 B-frags via cvt_pk + permlane32_swap (T12) ----
        u32 c_[8];
        #pragma unroll
        for (int j = 0; j < 8; ++j)
            asm("v_cvt_pk_bf16_f32 %0, %1, %2"
                : "=v"(c_[j]) : "v"(s[2*j]), "v"(s[2*j+1]));
        asm("v_permlane32_swap_b32 %0, %1" : "+v"(c_[0]), "+v"(c_[2]));
        asm("v_permlane32_swap_b32 %0, %1" : "+v"(c_[1]), "+v"(c_[3]));
        asm("v_permlane32_swap_b32 %0, %1" : "+v"(c_[4]), "+v"(c_[6]));
        asm("v_permlane32_swap_b32 %0, %1" : "+v"(c_[5]), "+v"(c_[7]));
        bf16x8 pf0, pf1;
        { u32 w[4] = {c_[0], c_[1], c_[2], c_[3]}; __builtin_memcpy(&pf0, w, 16); }
        { u32 w[4] = {c_[4], c_[5], c_[6], c_[7]}; __builtin_memcpy(&pf1, w, 16); }

        // ---- PV: batch the 8 V reads (overlays dead K regs), then burst ----
        bf16x8 vf[8];
        #pragma unroll
        for (int f = 0; f < 8; ++f)
            vf[f] = *(const bf16x8*)(bp + 8192 + f * 512);
        __builtin_amdgcn_s_setprio(1);
        O0 = MFMA_BF16(vf[0], pf0, O0);
        O1 = MFMA_BF16(vf[1], pf0, O1);
        O2 = MFMA_BF16(vf[2], pf0, O2);
        O3 = MFMA_BF16(vf[3], pf0, O3);
        O0 = MFMA_BF16(vf[4], pf1, O0);
        O1 = MFMA_BF16(vf[5], pf1, O1);
        O2 = MFMA_BF16(vf[6], pf1, O2);
        O3 = MFMA_BF16(vf[7], pf1, O3);
        __builtin_amdgcn_s_setprio(0);
        __syncthreads();
    }

    // ---- partial store (un-normalized O, plus m,l) ----
    l_run += __shfl_xor(l_run, 32);     // pair-lane partial sums
    float* prow = (half == 0 ? out0 : pout1) + (size_t)qrow * D_DIM;
    PSTORE_TILE(O0, 0); PSTORE_TILE(O1, 1);
    PSTORE_TILE(O2, 2); PSTORE_TILE(O3, 3);
    if (lane < 32) {
        pml[(size_t)half * B_ROWS + qrow] = make_float2(m_run, l_run);
    }
}

// ---------------------------------------------------------------------------
// Merge: out = (P0*w0 + P1*w1) / (l0*w0 + l1*w1), w_i = exp2(m_i - max).
// P0 lives in d_out (in-place read-modify-write per thread's own float4).
// ---------------------------------------------------------------------------
__global__ __launch_bounds__(256)
void merge_halves(const float* __restrict__ pout1,
                  const float2* __restrict__ pml,
                  float* __restrict__ out) {
    int idx  = blockIdx.x * 256 + threadIdx.x;   // 0 .. 2^20-1
    int row  = idx >> 5;
    int c4   = idx & 31;
    float2 a = pml[row];
    float2 b = pml[B_ROWS + row];
    float mn = fmaxf(a.x, b.x);
    float wa = EXP2F(a.x - mn);
    float wb = EXP2F(b.x - mn);
    float rinv = 1.0f / (a.y * wa + b.y * wb);
    float4* O = (float4*)(out + (size_t)row * D_DIM) + c4;
    const float4* P1 = (const float4*)(pout1 + (size_t)row * D_DIM) + c4;
    float4 p0 = *O, p1 = *P1;
    float4 v;
    v.x = (p0.x * wa + p1.x * wb) * rinv;
    v.y = (p0.y * wa + p1.y * wb) * rinv;
    v.z = (p0.z * wa + p1.z * wb) * rinv;
    v.w = (p0.w * wa + p1.w * wb) * rinv;
    *O = v;
}

extern "C" void kernel_launch(void* const* d_in, const int* in_sizes, int n_in,
                              void* d_out, int out_size, void* d_ws, size_t ws_size,
                              hipStream_t stream) {
    const float* local_stats = (const float*)d_in[0];   // [32768,128] f32
    const float* memory      = (const float*)d_in[1];   // [4096,128]  f32
    float* out = (float*)d_out;                         // [32768,128] f32

    // ws layout: kv frags 3MB | part-1 partial O 16MB | pml 0.5MB
    uint16_t* kv   = (uint16_t*)d_ws;
    float*   pout1 = (float*)((char*)d_ws + 3 * 1024 * 1024);
    float2*  pml   = (float2*)((char*)pout1 + (size_t)B_ROWS * D_DIM * 4);

    prep_frags<<<256, 256, 0, stream>>>(memory, kv);
    attn_main<<<512, 256, 0, stream>>>(local_stats, kv, out, pout1, pml);
    merge_halves<<<4096, 256, 0, stream>>>(pout1, pml, out);
}